// Round 18
// baseline (689.129 us; speedup 1.0000x reference)
//
#include <hip/hip_runtime.h>
#include <hip/hip_bf16.h>

// GPT forward: L=4, B=2, S=1024, D=768, H=12, DK=64, DI=3072, V=512
// R18 == R17 resubmitted (infra failure, no measurement):
//      k_pre 192-k tiles (27.6KB LDS, ~2x occupancy); ffin GEMM at 128x128
//      (barrier-amortization A/B). Rest frozen at R16 (best=680us).

#define TKN    2048
#define DMODEL 768
#define SEQ    1024
#define NH     12
#define DHEAD  64
#define DFF    3072
#define NL     4
#define NVOCAB 512
#define NQKV   2304

typedef unsigned short u16;
typedef __attribute__((ext_vector_type(4))) float f32x4;
typedef __attribute__((ext_vector_type(8))) short short8;
typedef __attribute__((ext_vector_type(4))) unsigned short us4;
typedef __attribute__((ext_vector_type(8))) unsigned short us8;

__device__ __forceinline__ u16 f2bf(float f) {
  unsigned u = __builtin_bit_cast(unsigned, f);
  u += 0x7fffu + ((u >> 16) & 1u);   // RNE
  return (u16)(u >> 16);
}

__device__ __forceinline__ float bf2f(u16 u) {
  unsigned v = ((unsigned)u) << 16;
  return __builtin_bit_cast(float, v);
}

__device__ __forceinline__ short8 mk8(us4 lo, us4 hi) {
  short8 r;
  r[0] = (short)lo[0]; r[1] = (short)lo[1]; r[2] = (short)lo[2]; r[3] = (short)lo[3];
  r[4] = (short)hi[0]; r[5] = (short)hi[1]; r[6] = (short)hi[2]; r[7] = (short)hi[3];
  return r;
}

__device__ __forceinline__ void gload16(const u16* g, u16* l) {
  __builtin_amdgcn_global_load_lds(
      (const __attribute__((address_space(1))) unsigned int*)g,
      (__attribute__((address_space(3))) unsigned int*)l, 16, 0, 0);
}

// ---------------- layernorm: one wave per row ----------------
__global__ __launch_bounds__(256) void k_ln(const float* __restrict__ h,
                                            const float* __restrict__ gam,
                                            const float* __restrict__ bet,
                                            u16* __restrict__ out) {
  const int w = threadIdx.x >> 6, lane = threadIdx.x & 63;
  const int row = blockIdx.x * 4 + w;
  const float* hr = h + (size_t)row * DMODEL;
  float4 v0 = *(const float4*)(hr + lane * 4);
  float4 v1 = *(const float4*)(hr + 256 + lane * 4);
  float4 v2 = *(const float4*)(hr + 512 + lane * 4);
  float s = v0.x + v0.y + v0.z + v0.w + v1.x + v1.y + v1.z + v1.w
          + v2.x + v2.y + v2.z + v2.w;
#pragma unroll
  for (int off = 32; off > 0; off >>= 1) s += __shfl_xor(s, off);
  float mu = s * (1.0f / DMODEL);
  float d[12] = {v0.x - mu, v0.y - mu, v0.z - mu, v0.w - mu,
                 v1.x - mu, v1.y - mu, v1.z - mu, v1.w - mu,
                 v2.x - mu, v2.y - mu, v2.z - mu, v2.w - mu};
  float q = 0.0f;
#pragma unroll
  for (int i = 0; i < 12; ++i) q += d[i] * d[i];
#pragma unroll
  for (int off = 32; off > 0; off >>= 1) q += __shfl_xor(q, off);
  float rstd = rsqrtf(q * (1.0f / DMODEL) + 1e-5f);
  size_t o = (size_t)row * DMODEL;
#pragma unroll
  for (int j = 0; j < 3; ++j) {
    float4 gv = *(const float4*)(gam + j * 256 + lane * 4);
    float4 bv = *(const float4*)(bet + j * 256 + lane * 4);
    us4 ov;
    ov[0] = f2bf(d[j * 4 + 0] * rstd * gv.x + bv.x);
    ov[1] = f2bf(d[j * 4 + 1] * rstd * gv.y + bv.y);
    ov[2] = f2bf(d[j * 4 + 2] * rstd * gv.z + bv.z);
    ov[3] = f2bf(d[j * 4 + 3] * rstd * gv.w + bv.w);
    *(us4*)(out + o + j * 256 + lane * 4) = ov;
  }
}

// ---------------- fused preamble: weight cvt+T (via LDS), embed, packb -------
// grid (865, NL). Weight tile = 64n x 192k.
// per-layer t<576: [0,144) QKV  [144,192) wo  [192,384) win  [384,576) wout
// l==0 only: [576,608) outw, [608,864) embed, t==864 packb.
// Phase 1: coalesced f32x4 reads -> convert -> us4 ds_writes into [64][216].
// Phase 2: barrier -> us8 ds_read -> 8-lane/row global stores (128B lines).
#define LDK2 216
__global__ __launch_bounds__(256) void k_pre(const float* __restrict__ wq,
                                             const float* __restrict__ wk,
                                             const float* __restrict__ wv,
                                             const float* __restrict__ wo,
                                             const float* __restrict__ win,
                                             const float* __restrict__ wout,
                                             const float* __restrict__ outw,
                                             const int* __restrict__ x,
                                             const float* __restrict__ emb,
                                             const float* __restrict__ pos,
                                             const float* __restrict__ bq,
                                             const float* __restrict__ bk,
                                             const float* __restrict__ bv,
                                             u16* __restrict__ wqkvT,
                                             u16* __restrict__ woT,
                                             u16* __restrict__ winT,
                                             u16* __restrict__ woutT,
                                             u16* __restrict__ outwT,
                                             float* __restrict__ h,
                                             float* __restrict__ bqkv) {
  __shared__ __align__(16) u16 tl[64 * LDK2];
  const int l = blockIdx.y;
  const int t = blockIdx.x;
  const int tid = threadIdx.x, lane = tid & 63, w = tid >> 6;

  if (t >= 576) {
    if (l != 0) return;
    if (t == 864) {                       // packb
      for (int i = tid; i < NL * NQKV; i += 256) {
        int ll = i / NQKV, j = i - ll * NQKV;
        float v = j < DMODEL ? bq[ll * DMODEL + j]
                : j < 2 * DMODEL ? bk[ll * DMODEL + j - DMODEL]
                : bv[ll * DMODEL + j - 2 * DMODEL];
        bqkv[i] = v;
      }
      return;
    }
    if (t >= 608) {
      // embed: block e covers 8 tokens, wave covers 2
      int e = t - 608;
#pragma unroll
      for (int tt = 0; tt < 2; ++tt) {
        int tok = e * 8 + w * 2 + tt;
        int s = tok & (SEQ - 1);
        int id = x[tok];
        const float* ep = emb + (size_t)id * DMODEL + lane * 4;
        const float* pp = pos + (size_t)s * DMODEL + lane * 4;
        float* hp = h + (size_t)tok * DMODEL + lane * 4;
#pragma unroll
        for (int j = 0; j < 3; ++j) {
          float4 a = *(const float4*)(ep + j * 256);
          float4 b = *(const float4*)(pp + j * 256);
          float4 o = {a.x + b.x, a.y + b.y, a.z + b.z, a.w + b.w};
          *(float4*)(hp + j * 256) = o;
        }
      }
      return;
    }
    // outw tile (t in [576,608))
    int t5 = t - 576, ntile = t5 >> 2, kc = t5 & 3;
    const float* src = outw;
    u16* dst = outwT;
    int ldS = NVOCAB, ldD = DMODEL;
    int scol0 = ntile * 64, n0 = ntile * 64, k0 = kc * 192;
    const int R = lane >> 2, c = lane & 3;
    const int kbase = w * 48 + c * 12;
    f32x4 v[12];
#pragma unroll
    for (int j = 0; j < 12; ++j)
      v[j] = *(const f32x4*)(src + (size_t)(k0 + kbase + j) * ldS + scol0 + R * 4);
#pragma unroll
    for (int i = 0; i < 4; ++i) {
      u16 ob[12];
#pragma unroll
      for (int j = 0; j < 12; ++j) ob[j] = f2bf(v[j][i]);
      u16* p = tl + (R * 4 + i) * LDK2 + kbase;
      *(us4*)p = *(us4*)&ob[0];
      *(us4*)(p + 4) = *(us4*)&ob[4];
      *(us4*)(p + 8) = *(us4*)&ob[8];
    }
    __syncthreads();
    const int rr = lane >> 3, ck = lane & 7;
#pragma unroll
    for (int rb = 0; rb < 2; ++rb) {
      const int row = w * 16 + rb * 8 + rr;
      u16* drow = dst + (size_t)(n0 + row) * ldD + k0;
      const u16* srow = tl + row * LDK2;
#pragma unroll
      for (int q = 0; q < 3; ++q)
        *(us8*)(drow + q * 64 + ck * 8) = *(const us8*)(srow + q * 64 + ck * 8);
    }
    return;
  }

  // ---- per-layer weight tile selection ----
  const size_t wDD = (size_t)DMODEL * DMODEL, wDF = (size_t)DMODEL * DFF;
  const float* src; u16* dst;
  int ldS, ldD, scol0, n0, k0;
  if (t < 144) {
    int ntile = t >> 2, kc = t & 3;
    int gn0 = ntile * 64, sel = ntile / 12;
    src = (sel == 0 ? wq : sel == 1 ? wk : wv) + l * wDD; ldS = DMODEL;
    dst = wqkvT + l * (size_t)NQKV * DMODEL; ldD = DMODEL;
    scol0 = gn0 - sel * DMODEL; n0 = gn0; k0 = kc * 192;
  } else if (t < 192) {
    int t2 = t - 144, ntile = t2 >> 2, kc = t2 & 3;
    src = wo + l * wDD; ldS = DMODEL;
    dst = woT + l * wDD; ldD = DMODEL;
    scol0 = ntile * 64; n0 = ntile * 64; k0 = kc * 192;
  } else if (t < 384) {
    int t3 = t - 192, ntile = t3 >> 2, kc = t3 & 3;
    src = win + l * wDF; ldS = DFF;
    dst = winT + l * wDF; ldD = DMODEL;
    scol0 = ntile * 64; n0 = ntile * 64; k0 = kc * 192;
  } else {
    int t4 = t - 384, ntile = t4 >> 4, kc = t4 & 15;
    src = wout + l * wDF; ldS = DMODEL;
    dst = woutT + l * wDF; ldD = DFF;
    scol0 = ntile * 64; n0 = ntile * 64; k0 = kc * 192;
  }

  // Phase 1: read f32 (coalesced 256B groups), convert, us4 ds_writes
  const int R = lane >> 2, c = lane & 3;
  const int kbase = w * 48 + c * 12;
  f32x4 v[12];
#pragma unroll
  for (int j = 0; j < 12; ++j)
    v[j] = *(const f32x4*)(src + (size_t)(k0 + kbase + j) * ldS + scol0 + R * 4);
#pragma unroll
  for (int i = 0; i < 4; ++i) {
    u16 ob[12];
#pragma unroll
    for (int j = 0; j < 12; ++j) ob[j] = f2bf(v[j][i]);
    u16* p = tl + (R * 4 + i) * LDK2 + kbase;
    *(us4*)p = *(us4*)&ob[0];
    *(us4*)(p + 4) = *(us4*)&ob[4];
    *(us4*)(p + 8) = *(us4*)&ob[8];
  }
  __syncthreads();

  // Phase 2: us8 ds_read, 128B-line global stores
  const int rr = lane >> 3, ck = lane & 7;
#pragma unroll
  for (int rb = 0; rb < 2; ++rb) {
    const int row = w * 16 + rb * 8 + rr;
    u16* drow = dst + (size_t)(n0 + row) * ldD + k0;
    const u16* srow = tl + row * LDK2;
#pragma unroll
    for (int q = 0; q < 3; ++q)
      *(us8*)(drow + q * 64 + ck * 8) = *(const us8*)(srow + q * 64 + ck * 8);
  }
}

// ---------------- GEMM (R12/R14 structure: BMxBN / 2-buffer / syncthreads) ----
// EP 0: bf16 = acc+bias          EP 1: atomicAdd f32 (+bias on split 0)
// EP 2: bf16 = gelu(acc+bias)    EP 3: f32 = acc
// EP 4: head-major QKV: q*(1/8)/k/v[b][h][s][64]
template <int EP, int BM, int BN>
__global__ __launch_bounds__(256) void k_mm(const u16* __restrict__ A,
                                            const u16* __restrict__ BT,
                                            const float* __restrict__ bias,
                                            void* __restrict__ outp,
                                            int N, int K) {
  constexpr int MI = BM / 32;
  constexpr int NJ = BN / 32;
  __shared__ __align__(16) u16 As[2][BM * 64];
  __shared__ __align__(16) u16 Bs[2][BN * 64];
  const int nbx = gridDim.x;
  int lin = blockIdx.y * nbx + blockIdx.x;
  const int chunk = (nbx * gridDim.y) >> 3;
  lin = (lin & 7) * chunk + (lin >> 3);
  const int bn = (lin % nbx) * BN, bm = (lin / nbx) * BM;

  const int tid = threadIdx.x, lane = tid & 63, wid = tid >> 6;
  const int g = lane >> 4, fl = lane & 15;
  const int wm = wid >> 1, wn = wid & 1;

  const int srow = wid * 8 + (lane >> 3);
  const int scol = ((lane & 7) ^ (lane >> 3)) << 3;
  const u16* ag = A + (size_t)(bm + srow) * K + scol;
  const u16* bg = BT + (size_t)(bn + srow) * K + scol;

  f32x4 acc[MI][NJ] = {};
  const int sw = (fl & 7) << 4;

  auto stage = [&](int buf, int kk) {
#pragma unroll
    for (int is = 0; is < MI; ++is)
      gload16(ag + kk + (size_t)is * 32 * K, &As[buf][wid * 512 + is * 2048]);
#pragma unroll
    for (int is = 0; is < NJ; ++is)
      gload16(bg + kk + (size_t)is * 32 * K, &Bs[buf][wid * 512 + is * 2048]);
  };

  const int ks = K / gridDim.z;
  const int kb0 = blockIdx.z * ks;
  const int nk = ks >> 6;
  stage(0, kb0);
  __syncthreads();
  int cur = 0;
  for (int kt = 0; kt < nk; ++kt) {
    if (kt + 1 < nk) stage(cur ^ 1, kb0 + ((kt + 1) << 6));
#pragma unroll
    for (int k0 = 0; k0 < 64; k0 += 32) {
      const int bo = (k0 + 4 * g) * 2;
      short8 af[MI], bf[NJ];
#pragma unroll
      for (int i = 0; i < MI; ++i) {
        const char* base = (const char*)&As[cur][(wm * (BM / 2) + i * 16 + fl) * 64];
        af[i] = mk8(*(const us4*)(base + (bo ^ sw)),
                    *(const us4*)(base + ((bo + 32) ^ sw)));
      }
#pragma unroll
      for (int j = 0; j < NJ; ++j) {
        const char* base = (const char*)&Bs[cur][(wn * (BN / 2) + j * 16 + fl) * 64];
        bf[j] = mk8(*(const us4*)(base + (bo ^ sw)),
                    *(const us4*)(base + ((bo + 32) ^ sw)));
      }
#pragma unroll
      for (int i = 0; i < MI; ++i)
#pragma unroll
        for (int j = 0; j < NJ; ++j)
          acc[i][j] = __builtin_amdgcn_mfma_f32_16x16x32_bf16(af[i], bf[j], acc[i][j], 0, 0, 0);
    }
    __syncthreads();
    cur ^= 1;
  }

  const int row0 = bm + wm * (BM / 2) + 4 * g;
  const int col0 = bn + wn * (BN / 2) + fl;
#pragma unroll
  for (int j = 0; j < NJ; ++j) {
    int col = col0 + j * 16;
    float bv = (EP == 3) ? 0.0f : bias[col];
    if (EP == 1 && blockIdx.z != 0) bv = 0.0f;
#pragma unroll
    for (int i = 0; i < MI; ++i) {
#pragma unroll
      for (int r = 0; r < 4; ++r) {
        int row = row0 + i * 16 + r;
        float val = acc[i][j][r] + bv;
        size_t idx = (size_t)row * N + col;
        if (EP == 0) {
          ((u16*)outp)[idx] = f2bf(val);
        } else if (EP == 1) {
          atomicAdd(&((float*)outp)[idx], val);
        } else if (EP == 2) {
          float t = 1.5957691216057308f * (val + 0.044715f * val * val * val);
          ((u16*)outp)[idx] = f2bf(val / (1.0f + __expf(-t)));
        } else if (EP == 3) {
          ((float*)outp)[idx] = val;
        } else {
          int sel = col / DMODEL;
          int cc = col - sel * DMODEL;
          int hh2 = cc >> 6, dk = cc & 63;
          int bb = row >> 10, ss = row & (SEQ - 1);
          if (sel == 0) val *= 0.125f;
          ((u16*)outp)[(size_t)sel * (TKN * DMODEL) +
                       (((size_t)(bb * NH + hh2) * SEQ + ss) << 6) + dk] = f2bf(val);
        }
      }
    }
  }
}

// ---------------- flash attention, head-major K/V, nsp = 1+qb/4 ----------------
__global__ __launch_bounds__(256) void k_attn(const u16* __restrict__ qh,
                                              u16* __restrict__ pO,
                                              float* __restrict__ pML,
                                              u16* __restrict__ O) {
  __shared__ u16 Vt[DHEAD * 68];
  int bid = blockIdx.x;
  int lin = (bid & 7) * 120 + (bid >> 3);     // XCD chunk swizzle (960 = 8*120)
  const int bh = lin / 40;
  const int idx = lin - bh * 40;
  int qb, sp;
  if (idx < 4)       { qb = idx;                     sp = 0; }
  else if (idx < 12) { qb = 4 + ((idx - 4) >> 1);    sp = (idx - 4) & 1; }
  else if (idx < 24) { int t = idx - 12; qb = 8 + t / 3;  sp = t - (t / 3) * 3; }
  else               { int t = idx - 24; qb = 12 + (t >> 2); sp = t & 3; }
  const int nsp = 1 + (qb >> 2), nt = qb + 1;
  const int t_lo = sp * nt / nsp, t_hi = (sp + 1) * nt / nsp;

  const int b = bh / NH, hh = bh % NH;
  const u16* kh = qh + TKN * DMODEL;
  const u16* vh = qh + 2 * (TKN * DMODEL);
  const size_t headbase = ((size_t)bh * SEQ) << 6;

  const int tid = threadIdx.x, lane = tid & 63, w = tid >> 6;
  const int g = lane >> 4, fl = lane & 15;
  const int qrow = qb * 64 + w * 16 + fl;

  short8 qf[2];
  {
    const u16* qp = qh + headbase + ((size_t)qrow << 6);
#pragma unroll
    for (int hf = 0; hf < 2; ++hf) {
      us4 lo = *(const us4*)(qp + hf * 32 + 4 * g);
      us4 hi = *(const us4*)(qp + hf * 32 + 16 + 4 * g);
      qf[hf] = mk8(lo, hi);
    }
  }

  float m = -1e30f, lsum = 0.0f;
  f32x4 oacc[4] = {};
  const int vr = tid >> 2, vd = (tid & 3) << 4;
  const u16* vbase = vh + headbase + ((size_t)vr << 6) + vd;
  const u16* kbase = kh + headbase;

  // prologue: stage V(t_lo)
  {
    const u16* vp = vbase + ((size_t)t_lo << 12);
    us4 vv[4];
#pragma unroll
    for (int qi = 0; qi < 4; ++qi) vv[qi] = *(const us4*)(vp + qi * 4);
#pragma unroll
    for (int qi = 0; qi < 4; ++qi)
#pragma unroll
      for (int i = 0; i < 4; ++i) Vt[(vd + qi * 4 + i) * 68 + vr] = vv[qi][i];
  }
  __syncthreads();

  for (int t64 = t_lo; t64 < t_hi; ++t64) {
    const u16* kb64 = kbase + ((size_t)t64 << 12);
    us4 kv[4][4];
#pragma unroll
    for (int q4 = 0; q4 < 4; ++q4) {
      const u16* kp = kb64 + ((q4 * 16 + fl) << 6);
#pragma unroll
      for (int j = 0; j < 4; ++j) kv[q4][j] = *(const us4*)(kp + j * 16 + 4 * g);
    }
    const bool pf = (t64 + 1 < t_hi);
    us4 vvn[4];
    if (pf) {
      const u16* vp = vbase + ((size_t)(t64 + 1) << 12);
#pragma unroll
      for (int qi = 0; qi < 4; ++qi) vvn[qi] = *(const us4*)(vp + qi * 4);
    }

    // QK^T: 8 MFMAs over 64 keys
    f32x4 sfr[4];
    __builtin_amdgcn_s_setprio(1);
#pragma unroll
    for (int sub = 0; sub < 4; ++sub) {
      short8 kf0 = mk8(kv[sub][0], kv[sub][1]);
      short8 kf1 = mk8(kv[sub][2], kv[sub][3]);
      f32x4 s = {};
      s = __builtin_amdgcn_mfma_f32_16x16x32_bf16(kf0, qf[0], s, 0, 0, 0);
      s = __builtin_amdgcn_mfma_f32_16x16x32_bf16(kf1, qf[1], s, 0, 0, 0);
      sfr[sub] = s;
    }
    __builtin_amdgcn_s_setprio(0);

    // merged 64-key softmax
    float sc[16];
    if (t64 == qb) {
#pragma unroll
      for (int sub = 0; sub < 4; ++sub)
#pragma unroll
        for (int r = 0; r < 4; ++r) {
          int key = t64 * 64 + sub * 16 + 4 * g + r;
          sc[sub * 4 + r] = (key <= qrow) ? sfr[sub][r] : -1e30f;
        }
    } else {
#pragma unroll
      for (int sub = 0; sub < 4; ++sub)
#pragma unroll
        for (int r = 0; r < 4; ++r) sc[sub * 4 + r] = sfr[sub][r];
    }
    float pmax = sc[0];
#pragma unroll
    for (int e = 1; e < 16; ++e) pmax = fmaxf(pmax, sc[e]);
    pmax = fmaxf(pmax, __shfl_xor(pmax, 16));
    pmax = fmaxf(pmax, __shfl_xor(pmax, 32));

    float p[16];
    if (__all(pmax <= m + 8.0f)) {
      float ps = 0.0f;
#pragma unroll
      for (int e = 0; e < 16; ++e) { p[e] = __expf(sc[e] - m); ps += p[e]; }
      ps += __shfl_xor(ps, 16);
      ps += __shfl_xor(ps, 32);
      lsum += ps;
    } else {
      float mnew = fmaxf(m, pmax);
      float corr = __expf(m - mnew);
      float ps = 0.0f;
#pragma unroll
      for (int e = 0; e < 16; ++e) { p[e] = __expf(sc[e] - mnew); ps += p[e]; }
      ps += __shfl_xor(ps, 16);
      ps += __shfl_xor(ps, 32);
      lsum = lsum * corr + ps;
      m = mnew;
      float cr[4];
#pragma unroll
      for (int r = 0; r < 4; ++r) cr[r] = __shfl(corr, 4 * g + r);
#pragma unroll
      for (int nb = 0; nb < 4; ++nb)
#pragma unroll
        for (int r = 0; r < 4; ++r) oacc[nb][r] *= cr[r];
    }

    short8 pf0, pf1;
#pragma unroll
    for (int e = 0; e < 8; ++e) { pf0[e] = (short)f2bf(p[e]); pf1[e] = (short)f2bf(p[8 + e]); }

    // PV: 8 MFMAs
    __builtin_amdgcn_s_setprio(1);
#pragma unroll
    for (int nb = 0; nb < 4; ++nb) {
      const u16* vtp = &Vt[(nb * 16 + fl) * 68 + 4 * g];
      short8 vf0 = mk8(*(const us4*)vtp, *(const us4*)(vtp + 16));
      short8 vf1 = mk8(*(const us4*)(vtp + 32), *(const us4*)(vtp + 48));
      oacc[nb] = __builtin_amdgcn_mfma_f32_16x16x32_bf16(pf0, vf0, oacc[nb], 0, 0, 0);
      oacc[nb] = __builtin_amdgcn_mfma_f32_16x16x32_bf16(pf1, vf1, oacc[nb], 0, 0, 0);
    }
    __builtin_amdgcn_s_setprio(0);

    if (pf) {
      __syncthreads();
#pragma unroll
      for (int qi = 0; qi < 4; ++qi)
#pragma unroll
        for (int i = 0; i < 4; ++i) Vt[(vd + qi * 4 + i) * 68 + vr] = vvn[qi][i];
      __syncthreads();
    }
  }

  if (nsp == 1) {
    float lr[4];
#pragma unroll
    for (int r = 0; r < 4; ++r) lr[r] = __shfl(lsum, 4 * g + r);
    const int orow0 = b * SEQ + qb * 64 + w * 16 + 4 * g;
#pragma unroll
    for (int nb = 0; nb < 4; ++nb) {
      int col = hh * DHEAD + nb * 16 + fl;
#pragma unroll
      for (int r = 0; r < 4; ++r)
        O[(size_t)(orow0 + r) * DMODEL + col] = f2bf(oacc[nb][r] / lr[r]);
    }
  } else {
    const size_t part = ((size_t)bh * 16 + qb) * 4 + sp;
    u16* ob = pO + part * 4096;
    float* ml = pML + part * 128;
#pragma unroll
    for (int nb = 0; nb < 4; ++nb)
#pragma unroll
      for (int r = 0; r < 4; ++r)
        ob[(w * 16 + 4 * g + r) * 64 + nb * 16 + fl] = f2bf(oacc[nb][r]);
    if (g == 0) {
      ml[w * 16 + fl] = m;
      ml[64 + w * 16 + fl] = lsum;
    }
  }
}

// ---------------- split reduce: qb >= 4 only ----------------
__global__ __launch_bounds__(256) void k_ared(const u16* __restrict__ pO,
                                              const float* __restrict__ pML,
                                              u16* __restrict__ O) {
  __shared__ float wgt[4][64];
  __shared__ float iLs[64];
  const int qb = blockIdx.x + 4, bh = blockIdx.y;
  const int nsp = 1 + (qb >> 2);
  const int b = bh / NH, hh = bh % NH;
  const int tid = threadIdx.x;
  const size_t p0 = ((size_t)bh * 16 + qb) * 4;
  if (tid < 64) {
    float M = -1e30f;
    for (int s = 0; s < nsp; ++s) M = fmaxf(M, pML[(p0 + s) * 128 + tid]);
    float L = 0.0f;
    for (int s = 0; s < nsp; ++s) {
      float wv = __expf(pML[(p0 + s) * 128 + tid] - M);
      wgt[s][tid] = wv;
      L += pML[(p0 + s) * 128 + 64 + tid] * wv;
    }
    iLs[tid] = 1.0f / L;
  }
  __syncthreads();
  for (int i = tid; i < 4096; i += 256) {
    int row = i >> 6, d = i & 63;
    float acc = 0.0f;
    for (int s = 0; s < nsp; ++s)
      acc += bf2f(pO[(p0 + s) * 4096 + i]) * wgt[s][row];
    O[(size_t)(b * SEQ + qb * 64 + row) * DMODEL + hh * DHEAD + d] = f2bf(acc * iLs[row]);
  }
}

// ---------------- launcher ----------------
extern "C" void kernel_launch(void* const* d_in, const int* in_sizes, int n_in,
                              void* d_out, int out_size, void* d_ws, size_t ws_size,
                              hipStream_t stream) {
  const int*   x    = (const int*)d_in[0];
  const float* emb  = (const float*)d_in[1];
  const float* pos  = (const float*)d_in[2];
  const float* ln1g = (const float*)d_in[3];
  const float* ln1b = (const float*)d_in[4];
  const float* wq   = (const float*)d_in[5];
  const float* bq   = (const float*)d_in[6];
  const float* wk   = (const float*)d_in[7];
  const float* bk   = (const float*)d_in[8];
  const float* wv   = (const float*)d_in[9];
  const float* bv   = (const float*)d_in[10];
  const float* wo   = (const float*)d_in[11];
  const float* bo   = (const float*)d_in[12];
  const float* ln2g = (const float*)d_in[13];
  const float* ln2b = (const float*)d_in[14];
  const float* win  = (const float*)d_in[15];
  const float* bin  = (const float*)d_in[16];
  const float* wout = (const float*)d_in[17];
  const float* bout = (const float*)d_in[18];
  const float* lnfg = (const float*)d_in[19];
  const float* lnfb = (const float*)d_in[20];
  const float* outw = (const float*)d_in[21];

  char* w8 = (char*)d_ws;
  float* h    = (float*)(w8);                  // 0        (6291456)
  u16* abuf   = (u16*)(w8 + 6291456);          // 6291456  (3145728)
  float* pML  = (float*)(w8 + 6291456);        //   alias abuf (786432 used)
  u16* qkvh   = (u16*)(w8 + 9437184);          // 9437184  (9437184)
  u16* ffbuf  = (u16*)(w8 + 9437184);          //   alias qkvh+obuf (12582912)
  u16* obuf   = (u16*)(w8 + 18874368);         // 18874368 (3145728)
  u16* outwT  = (u16*)(w8 + 22020096);         // 22020096 (786432)
  float* bqkv = (float*)(w8 + 22806528);       // 22806528 (36864)
  u16* pO     = (u16*)(w8 + 22843392);         // 22843392 (12582912)
  u16* wqkvT  = (u16*)(w8 + 48009216);         // 48009216 (14155776)
  u16* woT    = (u16*)(w8 + 62164992);         // 62164992 (4718592)
  u16* winT   = (u16*)(w8 + 66883584);         // 66883584 (18874368)
  u16* woutT  = (u16*)(w8 + 85757952);         // 85757952 (18874368)

  const size_t wDD = (size_t)DMODEL * DMODEL, wDF = (size_t)DMODEL * DFF;
  const size_t wQKV = (size_t)NQKV * DMODEL;

  k_pre<<<dim3(865, NL), 256, 0, stream>>>(
      wq, wk, wv, wo, win, wout, outw, x, emb, pos, bq, bk, bv,
      wqkvT, woT, winT, woutT, outwT, h, bqkv);

  for (int l = 0; l < NL; ++l) {
    k_ln<<<TKN / 4, 256, 0, stream>>>(h, ln1g + l * DMODEL, ln1b + l * DMODEL, abuf);
    k_mm<4, 128, 64><<<dim3(NQKV / 64, TKN / 128, 1), 256, 0, stream>>>(
        abuf, wqkvT + l * wQKV, bqkv + l * NQKV, qkvh, NQKV, DMODEL);
    k_attn<<<960, 256, 0, stream>>>(qkvh, pO, pML, obuf);
    k_ared<<<dim3(12, 2 * NH), 256, 0, stream>>>(pO, pML, obuf);
    k_mm<1, 128, 64><<<dim3(DMODEL / 64, TKN / 128, 2), 256, 0, stream>>>(
        obuf, woT + l * wDD, bo + l * DMODEL, h, DMODEL, DMODEL);
    k_ln<<<TKN / 4, 256, 0, stream>>>(h, ln2g + l * DMODEL, ln2b + l * DMODEL, abuf);
    k_mm<2, 128, 128><<<dim3(DFF / 128, TKN / 128, 1), 256, 0, stream>>>(
        abuf, winT + l * wDF, bin + l * DFF, ffbuf, DFF, DMODEL);
    k_mm<1, 128, 64><<<dim3(DMODEL / 64, TKN / 128, 4), 256, 0, stream>>>(
        ffbuf, woutT + l * wDF, bout + l * DMODEL, h, DMODEL, DFF);
  }

  k_ln<<<TKN / 4, 256, 0, stream>>>(h, lnfg, lnfb, abuf);
  k_mm<3, 64, 64><<<dim3(NVOCAB / 64, TKN / 64, 1), 256, 0, stream>>>(
      abuf, outwT, nullptr, d_out, NVOCAB, DMODEL);
}

// Round 21
// 680.450 us; speedup vs baseline: 1.0128x; 1.0128x over previous
//
#include <hip/hip_runtime.h>
#include <hip/hip_bf16.h>

// GPT forward: L=4, B=2, S=1024, D=768, H=12, DK=64, DI=3072, V=512
// R21 == R19/R20 resubmitted (two infra failures, never measured):
//      best-known config = R16 structure (ffin 128x64) + R18's 192k-tile k_pre.

#define TKN    2048
#define DMODEL 768
#define SEQ    1024
#define NH     12
#define DHEAD  64
#define DFF    3072
#define NL     4
#define NVOCAB 512
#define NQKV   2304

typedef unsigned short u16;
typedef __attribute__((ext_vector_type(4))) float f32x4;
typedef __attribute__((ext_vector_type(8))) short short8;
typedef __attribute__((ext_vector_type(4))) unsigned short us4;
typedef __attribute__((ext_vector_type(8))) unsigned short us8;

__device__ __forceinline__ u16 f2bf(float f) {
  unsigned u = __builtin_bit_cast(unsigned, f);
  u += 0x7fffu + ((u >> 16) & 1u);   // RNE
  return (u16)(u >> 16);
}

__device__ __forceinline__ float bf2f(u16 u) {
  unsigned v = ((unsigned)u) << 16;
  return __builtin_bit_cast(float, v);
}

__device__ __forceinline__ short8 mk8(us4 lo, us4 hi) {
  short8 r;
  r[0] = (short)lo[0]; r[1] = (short)lo[1]; r[2] = (short)lo[2]; r[3] = (short)lo[3];
  r[4] = (short)hi[0]; r[5] = (short)hi[1]; r[6] = (short)hi[2]; r[7] = (short)hi[3];
  return r;
}

__device__ __forceinline__ void gload16(const u16* g, u16* l) {
  __builtin_amdgcn_global_load_lds(
      (const __attribute__((address_space(1))) unsigned int*)g,
      (__attribute__((address_space(3))) unsigned int*)l, 16, 0, 0);
}

// ---------------- layernorm: one wave per row ----------------
__global__ __launch_bounds__(256) void k_ln(const float* __restrict__ h,
                                            const float* __restrict__ gam,
                                            const float* __restrict__ bet,
                                            u16* __restrict__ out) {
  const int w = threadIdx.x >> 6, lane = threadIdx.x & 63;
  const int row = blockIdx.x * 4 + w;
  const float* hr = h + (size_t)row * DMODEL;
  float4 v0 = *(const float4*)(hr + lane * 4);
  float4 v1 = *(const float4*)(hr + 256 + lane * 4);
  float4 v2 = *(const float4*)(hr + 512 + lane * 4);
  float s = v0.x + v0.y + v0.z + v0.w + v1.x + v1.y + v1.z + v1.w
          + v2.x + v2.y + v2.z + v2.w;
#pragma unroll
  for (int off = 32; off > 0; off >>= 1) s += __shfl_xor(s, off);
  float mu = s * (1.0f / DMODEL);
  float d[12] = {v0.x - mu, v0.y - mu, v0.z - mu, v0.w - mu,
                 v1.x - mu, v1.y - mu, v1.z - mu, v1.w - mu,
                 v2.x - mu, v2.y - mu, v2.z - mu, v2.w - mu};
  float q = 0.0f;
#pragma unroll
  for (int i = 0; i < 12; ++i) q += d[i] * d[i];
#pragma unroll
  for (int off = 32; off > 0; off >>= 1) q += __shfl_xor(q, off);
  float rstd = rsqrtf(q * (1.0f / DMODEL) + 1e-5f);
  size_t o = (size_t)row * DMODEL;
#pragma unroll
  for (int j = 0; j < 3; ++j) {
    float4 gv = *(const float4*)(gam + j * 256 + lane * 4);
    float4 bv = *(const float4*)(bet + j * 256 + lane * 4);
    us4 ov;
    ov[0] = f2bf(d[j * 4 + 0] * rstd * gv.x + bv.x);
    ov[1] = f2bf(d[j * 4 + 1] * rstd * gv.y + bv.y);
    ov[2] = f2bf(d[j * 4 + 2] * rstd * gv.z + bv.z);
    ov[3] = f2bf(d[j * 4 + 3] * rstd * gv.w + bv.w);
    *(us4*)(out + o + j * 256 + lane * 4) = ov;
  }
}

// ---------------- fused preamble: weight cvt+T (via LDS), embed, packb -------
// grid (865, NL). Weight tile = 64n x 192k.
// per-layer t<576: [0,144) QKV  [144,192) wo  [192,384) win  [384,576) wout
// l==0 only: [576,608) outw, [608,864) embed, t==864 packb.
#define LDK2 216
__global__ __launch_bounds__(256) void k_pre(const float* __restrict__ wq,
                                             const float* __restrict__ wk,
                                             const float* __restrict__ wv,
                                             const float* __restrict__ wo,
                                             const float* __restrict__ win,
                                             const float* __restrict__ wout,
                                             const float* __restrict__ outw,
                                             const int* __restrict__ x,
                                             const float* __restrict__ emb,
                                             const float* __restrict__ pos,
                                             const float* __restrict__ bq,
                                             const float* __restrict__ bk,
                                             const float* __restrict__ bv,
                                             u16* __restrict__ wqkvT,
                                             u16* __restrict__ woT,
                                             u16* __restrict__ winT,
                                             u16* __restrict__ woutT,
                                             u16* __restrict__ outwT,
                                             float* __restrict__ h,
                                             float* __restrict__ bqkv) {
  __shared__ __align__(16) u16 tl[64 * LDK2];
  const int l = blockIdx.y;
  const int t = blockIdx.x;
  const int tid = threadIdx.x, lane = tid & 63, w = tid >> 6;

  if (t >= 576) {
    if (l != 0) return;
    if (t == 864) {                       // packb
      for (int i = tid; i < NL * NQKV; i += 256) {
        int ll = i / NQKV, j = i - ll * NQKV;
        float v = j < DMODEL ? bq[ll * DMODEL + j]
                : j < 2 * DMODEL ? bk[ll * DMODEL + j - DMODEL]
                : bv[ll * DMODEL + j - 2 * DMODEL];
        bqkv[i] = v;
      }
      return;
    }
    if (t >= 608) {
      int e = t - 608;
#pragma unroll
      for (int tt = 0; tt < 2; ++tt) {
        int tok = e * 8 + w * 2 + tt;
        int s = tok & (SEQ - 1);
        int id = x[tok];
        const float* ep = emb + (size_t)id * DMODEL + lane * 4;
        const float* pp = pos + (size_t)s * DMODEL + lane * 4;
        float* hp = h + (size_t)tok * DMODEL + lane * 4;
#pragma unroll
        for (int j = 0; j < 3; ++j) {
          float4 a = *(const float4*)(ep + j * 256);
          float4 b = *(const float4*)(pp + j * 256);
          float4 o = {a.x + b.x, a.y + b.y, a.z + b.z, a.w + b.w};
          *(float4*)(hp + j * 256) = o;
        }
      }
      return;
    }
    // outw tile (t in [576,608))
    int t5 = t - 576, ntile = t5 >> 2, kc = t5 & 3;
    const float* src = outw;
    u16* dst = outwT;
    int ldS = NVOCAB, ldD = DMODEL;
    int scol0 = ntile * 64, n0 = ntile * 64, k0 = kc * 192;
    const int R = lane >> 2, c = lane & 3;
    const int kbase = w * 48 + c * 12;
    f32x4 v[12];
#pragma unroll
    for (int j = 0; j < 12; ++j)
      v[j] = *(const f32x4*)(src + (size_t)(k0 + kbase + j) * ldS + scol0 + R * 4);
#pragma unroll
    for (int i = 0; i < 4; ++i) {
      u16 ob[12];
#pragma unroll
      for (int j = 0; j < 12; ++j) ob[j] = f2bf(v[j][i]);
      u16* p = tl + (R * 4 + i) * LDK2 + kbase;
      *(us4*)p = *(us4*)&ob[0];
      *(us4*)(p + 4) = *(us4*)&ob[4];
      *(us4*)(p + 8) = *(us4*)&ob[8];
    }
    __syncthreads();
    const int rr = lane >> 3, ck = lane & 7;
#pragma unroll
    for (int rb = 0; rb < 2; ++rb) {
      const int row = w * 16 + rb * 8 + rr;
      u16* drow = dst + (size_t)(n0 + row) * ldD + k0;
      const u16* srow = tl + row * LDK2;
#pragma unroll
      for (int q = 0; q < 3; ++q)
        *(us8*)(drow + q * 64 + ck * 8) = *(const us8*)(srow + q * 64 + ck * 8);
    }
    return;
  }

  // ---- per-layer weight tile selection ----
  const size_t wDD = (size_t)DMODEL * DMODEL, wDF = (size_t)DMODEL * DFF;
  const float* src; u16* dst;
  int ldS, ldD, scol0, n0, k0;
  if (t < 144) {
    int ntile = t >> 2, kc = t & 3;
    int gn0 = ntile * 64, sel = ntile / 12;
    src = (sel == 0 ? wq : sel == 1 ? wk : wv) + l * wDD; ldS = DMODEL;
    dst = wqkvT + l * (size_t)NQKV * DMODEL; ldD = DMODEL;
    scol0 = gn0 - sel * DMODEL; n0 = gn0; k0 = kc * 192;
  } else if (t < 192) {
    int t2 = t - 144, ntile = t2 >> 2, kc = t2 & 3;
    src = wo + l * wDD; ldS = DMODEL;
    dst = woT + l * wDD; ldD = DMODEL;
    scol0 = ntile * 64; n0 = ntile * 64; k0 = kc * 192;
  } else if (t < 384) {
    int t3 = t - 192, ntile = t3 >> 2, kc = t3 & 3;
    src = win + l * wDF; ldS = DFF;
    dst = winT + l * wDF; ldD = DMODEL;
    scol0 = ntile * 64; n0 = ntile * 64; k0 = kc * 192;
  } else {
    int t4 = t - 384, ntile = t4 >> 4, kc = t4 & 15;
    src = wout + l * wDF; ldS = DMODEL;
    dst = woutT + l * wDF; ldD = DFF;
    scol0 = ntile * 64; n0 = ntile * 64; k0 = kc * 192;
  }

  // Phase 1: read f32 (coalesced 256B groups), convert, us4 ds_writes
  const int R = lane >> 2, c = lane & 3;
  const int kbase = w * 48 + c * 12;
  f32x4 v[12];
#pragma unroll
  for (int j = 0; j < 12; ++j)
    v[j] = *(const f32x4*)(src + (size_t)(k0 + kbase + j) * ldS + scol0 + R * 4);
#pragma unroll
  for (int i = 0; i < 4; ++i) {
    u16 ob[12];
#pragma unroll
    for (int j = 0; j < 12; ++j) ob[j] = f2bf(v[j][i]);
    u16* p = tl + (R * 4 + i) * LDK2 + kbase;
    *(us4*)p = *(us4*)&ob[0];
    *(us4*)(p + 4) = *(us4*)&ob[4];
    *(us4*)(p + 8) = *(us4*)&ob[8];
  }
  __syncthreads();

  // Phase 2: us8 ds_read, 128B-line global stores
  const int rr = lane >> 3, ck = lane & 7;
#pragma unroll
  for (int rb = 0; rb < 2; ++rb) {
    const int row = w * 16 + rb * 8 + rr;
    u16* drow = dst + (size_t)(n0 + row) * ldD + k0;
    const u16* srow = tl + row * LDK2;
#pragma unroll
    for (int q = 0; q < 3; ++q)
      *(us8*)(drow + q * 64 + ck * 8) = *(const us8*)(srow + q * 64 + ck * 8);
  }
}

// ---------------- GEMM (R12/R14 structure: BMxBN / 2-buffer / syncthreads) ----
// EP 0: bf16 = acc+bias          EP 1: atomicAdd f32 (+bias on split 0)
// EP 2: bf16 = gelu(acc+bias)    EP 3: f32 = acc
// EP 4: head-major QKV: q*(1/8)/k/v[b][h][s][64]
template <int EP, int BM, int BN>
__global__ __launch_bounds__(256) void k_mm(const u16* __restrict__ A,
                                            const u16* __restrict__ BT,
                                            const float* __restrict__ bias,
                                            void* __restrict__ outp,
                                            int N, int K) {
  constexpr int MI = BM / 32;
  constexpr int NJ = BN / 32;
  __shared__ __align__(16) u16 As[2][BM * 64];
  __shared__ __align__(16) u16 Bs[2][BN * 64];
  const int nbx = gridDim.x;
  int lin = blockIdx.y * nbx + blockIdx.x;
  const int chunk = (nbx * gridDim.y) >> 3;
  lin = (lin & 7) * chunk + (lin >> 3);
  const int bn = (lin % nbx) * BN, bm = (lin / nbx) * BM;

  const int tid = threadIdx.x, lane = tid & 63, wid = tid >> 6;
  const int g = lane >> 4, fl = lane & 15;
  const int wm = wid >> 1, wn = wid & 1;

  const int srow = wid * 8 + (lane >> 3);
  const int scol = ((lane & 7) ^ (lane >> 3)) << 3;
  const u16* ag = A + (size_t)(bm + srow) * K + scol;
  const u16* bg = BT + (size_t)(bn + srow) * K + scol;

  f32x4 acc[MI][NJ] = {};
  const int sw = (fl & 7) << 4;

  auto stage = [&](int buf, int kk) {
#pragma unroll
    for (int is = 0; is < MI; ++is)
      gload16(ag + kk + (size_t)is * 32 * K, &As[buf][wid * 512 + is * 2048]);
#pragma unroll
    for (int is = 0; is < NJ; ++is)
      gload16(bg + kk + (size_t)is * 32 * K, &Bs[buf][wid * 512 + is * 2048]);
  };

  const int ks = K / gridDim.z;
  const int kb0 = blockIdx.z * ks;
  const int nk = ks >> 6;
  stage(0, kb0);
  __syncthreads();
  int cur = 0;
  for (int kt = 0; kt < nk; ++kt) {
    if (kt + 1 < nk) stage(cur ^ 1, kb0 + ((kt + 1) << 6));
#pragma unroll
    for (int k0 = 0; k0 < 64; k0 += 32) {
      const int bo = (k0 + 4 * g) * 2;
      short8 af[MI], bf[NJ];
#pragma unroll
      for (int i = 0; i < MI; ++i) {
        const char* base = (const char*)&As[cur][(wm * (BM / 2) + i * 16 + fl) * 64];
        af[i] = mk8(*(const us4*)(base + (bo ^ sw)),
                    *(const us4*)(base + ((bo + 32) ^ sw)));
      }
#pragma unroll
      for (int j = 0; j < NJ; ++j) {
        const char* base = (const char*)&Bs[cur][(wn * (BN / 2) + j * 16 + fl) * 64];
        bf[j] = mk8(*(const us4*)(base + (bo ^ sw)),
                    *(const us4*)(base + ((bo + 32) ^ sw)));
      }
#pragma unroll
      for (int i = 0; i < MI; ++i)
#pragma unroll
        for (int j = 0; j < NJ; ++j)
          acc[i][j] = __builtin_amdgcn_mfma_f32_16x16x32_bf16(af[i], bf[j], acc[i][j], 0, 0, 0);
    }
    __syncthreads();
    cur ^= 1;
  }

  const int row0 = bm + wm * (BM / 2) + 4 * g;
  const int col0 = bn + wn * (BN / 2) + fl;
#pragma unroll
  for (int j = 0; j < NJ; ++j) {
    int col = col0 + j * 16;
    float bv = (EP == 3) ? 0.0f : bias[col];
    if (EP == 1 && blockIdx.z != 0) bv = 0.0f;
#pragma unroll
    for (int i = 0; i < MI; ++i) {
#pragma unroll
      for (int r = 0; r < 4; ++r) {
        int row = row0 + i * 16 + r;
        float val = acc[i][j][r] + bv;
        size_t idx = (size_t)row * N + col;
        if (EP == 0) {
          ((u16*)outp)[idx] = f2bf(val);
        } else if (EP == 1) {
          atomicAdd(&((float*)outp)[idx], val);
        } else if (EP == 2) {
          float t = 1.5957691216057308f * (val + 0.044715f * val * val * val);
          ((u16*)outp)[idx] = f2bf(val / (1.0f + __expf(-t)));
        } else if (EP == 3) {
          ((float*)outp)[idx] = val;
        } else {
          int sel = col / DMODEL;
          int cc = col - sel * DMODEL;
          int hh2 = cc >> 6, dk = cc & 63;
          int bb = row >> 10, ss = row & (SEQ - 1);
          if (sel == 0) val *= 0.125f;
          ((u16*)outp)[(size_t)sel * (TKN * DMODEL) +
                       (((size_t)(bb * NH + hh2) * SEQ + ss) << 6) + dk] = f2bf(val);
        }
      }
    }
  }
}

// ---------------- flash attention, head-major K/V, nsp = 1+qb/4 ----------------
__global__ __launch_bounds__(256) void k_attn(const u16* __restrict__ qh,
                                              u16* __restrict__ pO,
                                              float* __restrict__ pML,
                                              u16* __restrict__ O) {
  __shared__ u16 Vt[DHEAD * 68];
  int bid = blockIdx.x;
  int lin = (bid & 7) * 120 + (bid >> 3);     // XCD chunk swizzle (960 = 8*120)
  const int bh = lin / 40;
  const int idx = lin - bh * 40;
  int qb, sp;
  if (idx < 4)       { qb = idx;                     sp = 0; }
  else if (idx < 12) { qb = 4 + ((idx - 4) >> 1);    sp = (idx - 4) & 1; }
  else if (idx < 24) { int t = idx - 12; qb = 8 + t / 3;  sp = t - (t / 3) * 3; }
  else               { int t = idx - 24; qb = 12 + (t >> 2); sp = t & 3; }
  const int nsp = 1 + (qb >> 2), nt = qb + 1;
  const int t_lo = sp * nt / nsp, t_hi = (sp + 1) * nt / nsp;

  const int b = bh / NH, hh = bh % NH;
  const u16* kh = qh + TKN * DMODEL;
  const u16* vh = qh + 2 * (TKN * DMODEL);
  const size_t headbase = ((size_t)bh * SEQ) << 6;

  const int tid = threadIdx.x, lane = tid & 63, w = tid >> 6;
  const int g = lane >> 4, fl = lane & 15;
  const int qrow = qb * 64 + w * 16 + fl;

  short8 qf[2];
  {
    const u16* qp = qh + headbase + ((size_t)qrow << 6);
#pragma unroll
    for (int hf = 0; hf < 2; ++hf) {
      us4 lo = *(const us4*)(qp + hf * 32 + 4 * g);
      us4 hi = *(const us4*)(qp + hf * 32 + 16 + 4 * g);
      qf[hf] = mk8(lo, hi);
    }
  }

  float m = -1e30f, lsum = 0.0f;
  f32x4 oacc[4] = {};
  const int vr = tid >> 2, vd = (tid & 3) << 4;
  const u16* vbase = vh + headbase + ((size_t)vr << 6) + vd;
  const u16* kbase = kh + headbase;

  // prologue: stage V(t_lo)
  {
    const u16* vp = vbase + ((size_t)t_lo << 12);
    us4 vv[4];
#pragma unroll
    for (int qi = 0; qi < 4; ++qi) vv[qi] = *(const us4*)(vp + qi * 4);
#pragma unroll
    for (int qi = 0; qi < 4; ++qi)
#pragma unroll
      for (int i = 0; i < 4; ++i) Vt[(vd + qi * 4 + i) * 68 + vr] = vv[qi][i];
  }
  __syncthreads();

  for (int t64 = t_lo; t64 < t_hi; ++t64) {
    const u16* kb64 = kbase + ((size_t)t64 << 12);
    us4 kv[4][4];
#pragma unroll
    for (int q4 = 0; q4 < 4; ++q4) {
      const u16* kp = kb64 + ((q4 * 16 + fl) << 6);
#pragma unroll
      for (int j = 0; j < 4; ++j) kv[q4][j] = *(const us4*)(kp + j * 16 + 4 * g);
    }
    const bool pf = (t64 + 1 < t_hi);
    us4 vvn[4];
    if (pf) {
      const u16* vp = vbase + ((size_t)(t64 + 1) << 12);
#pragma unroll
      for (int qi = 0; qi < 4; ++qi) vvn[qi] = *(const us4*)(vp + qi * 4);
    }

    // QK^T: 8 MFMAs over 64 keys
    f32x4 sfr[4];
    __builtin_amdgcn_s_setprio(1);
#pragma unroll
    for (int sub = 0; sub < 4; ++sub) {
      short8 kf0 = mk8(kv[sub][0], kv[sub][1]);
      short8 kf1 = mk8(kv[sub][2], kv[sub][3]);
      f32x4 s = {};
      s = __builtin_amdgcn_mfma_f32_16x16x32_bf16(kf0, qf[0], s, 0, 0, 0);
      s = __builtin_amdgcn_mfma_f32_16x16x32_bf16(kf1, qf[1], s, 0, 0, 0);
      sfr[sub] = s;
    }
    __builtin_amdgcn_s_setprio(0);

    // merged 64-key softmax
    float sc[16];
    if (t64 == qb) {
#pragma unroll
      for (int sub = 0; sub < 4; ++sub)
#pragma unroll
        for (int r = 0; r < 4; ++r) {
          int key = t64 * 64 + sub * 16 + 4 * g + r;
          sc[sub * 4 + r] = (key <= qrow) ? sfr[sub][r] : -1e30f;
        }
    } else {
#pragma unroll
      for (int sub = 0; sub < 4; ++sub)
#pragma unroll
        for (int r = 0; r < 4; ++r) sc[sub * 4 + r] = sfr[sub][r];
    }
    float pmax = sc[0];
#pragma unroll
    for (int e = 1; e < 16; ++e) pmax = fmaxf(pmax, sc[e]);
    pmax = fmaxf(pmax, __shfl_xor(pmax, 16));
    pmax = fmaxf(pmax, __shfl_xor(pmax, 32));

    float p[16];
    if (__all(pmax <= m + 8.0f)) {
      float ps = 0.0f;
#pragma unroll
      for (int e = 0; e < 16; ++e) { p[e] = __expf(sc[e] - m); ps += p[e]; }
      ps += __shfl_xor(ps, 16);
      ps += __shfl_xor(ps, 32);
      lsum += ps;
    } else {
      float mnew = fmaxf(m, pmax);
      float corr = __expf(m - mnew);
      float ps = 0.0f;
#pragma unroll
      for (int e = 0; e < 16; ++e) { p[e] = __expf(sc[e] - mnew); ps += p[e]; }
      ps += __shfl_xor(ps, 16);
      ps += __shfl_xor(ps, 32);
      lsum = lsum * corr + ps;
      m = mnew;
      float cr[4];
#pragma unroll
      for (int r = 0; r < 4; ++r) cr[r] = __shfl(corr, 4 * g + r);
#pragma unroll
      for (int nb = 0; nb < 4; ++nb)
#pragma unroll
        for (int r = 0; r < 4; ++r) oacc[nb][r] *= cr[r];
    }

    short8 pf0, pf1;
#pragma unroll
    for (int e = 0; e < 8; ++e) { pf0[e] = (short)f2bf(p[e]); pf1[e] = (short)f2bf(p[8 + e]); }

    // PV: 8 MFMAs
    __builtin_amdgcn_s_setprio(1);
#pragma unroll
    for (int nb = 0; nb < 4; ++nb) {
      const u16* vtp = &Vt[(nb * 16 + fl) * 68 + 4 * g];
      short8 vf0 = mk8(*(const us4*)vtp, *(const us4*)(vtp + 16));
      short8 vf1 = mk8(*(const us4*)(vtp + 32), *(const us4*)(vtp + 48));
      oacc[nb] = __builtin_amdgcn_mfma_f32_16x16x32_bf16(pf0, vf0, oacc[nb], 0, 0, 0);
      oacc[nb] = __builtin_amdgcn_mfma_f32_16x16x32_bf16(pf1, vf1, oacc[nb], 0, 0, 0);
    }
    __builtin_amdgcn_s_setprio(0);

    if (pf) {
      __syncthreads();
#pragma unroll
      for (int qi = 0; qi < 4; ++qi)
#pragma unroll
        for (int i = 0; i < 4; ++i) Vt[(vd + qi * 4 + i) * 68 + vr] = vvn[qi][i];
      __syncthreads();
    }
  }

  if (nsp == 1) {
    float lr[4];
#pragma unroll
    for (int r = 0; r < 4; ++r) lr[r] = __shfl(lsum, 4 * g + r);
    const int orow0 = b * SEQ + qb * 64 + w * 16 + 4 * g;
#pragma unroll
    for (int nb = 0; nb < 4; ++nb) {
      int col = hh * DHEAD + nb * 16 + fl;
#pragma unroll
      for (int r = 0; r < 4; ++r)
        O[(size_t)(orow0 + r) * DMODEL + col] = f2bf(oacc[nb][r] / lr[r]);
    }
  } else {
    const size_t part = ((size_t)bh * 16 + qb) * 4 + sp;
    u16* ob = pO + part * 4096;
    float* ml = pML + part * 128;
#pragma unroll
    for (int nb = 0; nb < 4; ++nb)
#pragma unroll
      for (int r = 0; r < 4; ++r)
        ob[(w * 16 + 4 * g + r) * 64 + nb * 16 + fl] = f2bf(oacc[nb][r]);
    if (g == 0) {
      ml[w * 16 + fl] = m;
      ml[64 + w * 16 + fl] = lsum;
    }
  }
}

// ---------------- split reduce: qb >= 4 only ----------------
__global__ __launch_bounds__(256) void k_ared(const u16* __restrict__ pO,
                                              const float* __restrict__ pML,
                                              u16* __restrict__ O) {
  __shared__ float wgt[4][64];
  __shared__ float iLs[64];
  const int qb = blockIdx.x + 4, bh = blockIdx.y;
  const int nsp = 1 + (qb >> 2);
  const int b = bh / NH, hh = bh % NH;
  const int tid = threadIdx.x;
  const size_t p0 = ((size_t)bh * 16 + qb) * 4;
  if (tid < 64) {
    float M = -1e30f;
    for (int s = 0; s < nsp; ++s) M = fmaxf(M, pML[(p0 + s) * 128 + tid]);
    float L = 0.0f;
    for (int s = 0; s < nsp; ++s) {
      float wv = __expf(pML[(p0 + s) * 128 + tid] - M);
      wgt[s][tid] = wv;
      L += pML[(p0 + s) * 128 + 64 + tid] * wv;
    }
    iLs[tid] = 1.0f / L;
  }
  __syncthreads();
  for (int i = tid; i < 4096; i += 256) {
    int row = i >> 6, d = i & 63;
    float acc = 0.0f;
    for (int s = 0; s < nsp; ++s)
      acc += bf2f(pO[(p0 + s) * 4096 + i]) * wgt[s][row];
    O[(size_t)(b * SEQ + qb * 64 + row) * DMODEL + hh * DHEAD + d] = f2bf(acc * iLs[row]);
  }
}

// ---------------- launcher ----------------
extern "C" void kernel_launch(void* const* d_in, const int* in_sizes, int n_in,
                              void* d_out, int out_size, void* d_ws, size_t ws_size,
                              hipStream_t stream) {
  const int*   x    = (const int*)d_in[0];
  const float* emb  = (const float*)d_in[1];
  const float* pos  = (const float*)d_in[2];
  const float* ln1g = (const float*)d_in[3];
  const float* ln1b = (const float*)d_in[4];
  const float* wq   = (const float*)d_in[5];
  const float* bq   = (const float*)d_in[6];
  const float* wk   = (const float*)d_in[7];
  const float* bk   = (const float*)d_in[8];
  const float* wv   = (const float*)d_in[9];
  const float* bv   = (const float*)d_in[10];
  const float* wo   = (const float*)d_in[11];
  const float* bo   = (const float*)d_in[12];
  const float* ln2g = (const float*)d_in[13];
  const float* ln2b = (const float*)d_in[14];
  const float* win  = (const float*)d_in[15];
  const float* bin  = (const float*)d_in[16];
  const float* wout = (const float*)d_in[17];
  const float* bout = (const float*)d_in[18];
  const float* lnfg = (const float*)d_in[19];
  const float* lnfb = (const float*)d_in[20];
  const float* outw = (const float*)d_in[21];

  char* w8 = (char*)d_ws;
  float* h    = (float*)(w8);                  // 0        (6291456)
  u16* abuf   = (u16*)(w8 + 6291456);          // 6291456  (3145728)
  float* pML  = (float*)(w8 + 6291456);        //   alias abuf (786432 used)
  u16* qkvh   = (u16*)(w8 + 9437184);          // 9437184  (9437184)
  u16* ffbuf  = (u16*)(w8 + 9437184);          //   alias qkvh+obuf (12582912)
  u16* obuf   = (u16*)(w8 + 18874368);         // 18874368 (3145728)
  u16* outwT  = (u16*)(w8 + 22020096);         // 22020096 (786432)
  float* bqkv = (float*)(w8 + 22806528);       // 22806528 (36864)
  u16* pO     = (u16*)(w8 + 22843392);         // 22843392 (12582912)
  u16* wqkvT  = (u16*)(w8 + 48009216);         // 48009216 (14155776)
  u16* woT    = (u16*)(w8 + 62164992);         // 62164992 (4718592)
  u16* winT   = (u16*)(w8 + 66883584);         // 66883584 (18874368)
  u16* woutT  = (u16*)(w8 + 85757952);         // 85757952 (18874368)

  const size_t wDD = (size_t)DMODEL * DMODEL, wDF = (size_t)DMODEL * DFF;
  const size_t wQKV = (size_t)NQKV * DMODEL;

  k_pre<<<dim3(865, NL), 256, 0, stream>>>(
      wq, wk, wv, wo, win, wout, outw, x, emb, pos, bq, bk, bv,
      wqkvT, woT, winT, woutT, outwT, h, bqkv);

  for (int l = 0; l < NL; ++l) {
    k_ln<<<TKN / 4, 256, 0, stream>>>(h, ln1g + l * DMODEL, ln1b + l * DMODEL, abuf);
    k_mm<4, 128, 64><<<dim3(NQKV / 64, TKN / 128, 1), 256, 0, stream>>>(
        abuf, wqkvT + l * wQKV, bqkv + l * NQKV, qkvh, NQKV, DMODEL);
    k_attn<<<960, 256, 0, stream>>>(qkvh, pO, pML, obuf);
    k_ared<<<dim3(12, 2 * NH), 256, 0, stream>>>(pO, pML, obuf);
    k_mm<1, 128, 64><<<dim3(DMODEL / 64, TKN / 128, 2), 256, 0, stream>>>(
        obuf, woT + l * wDD, bo + l * DMODEL, h, DMODEL, DMODEL);
    k_ln<<<TKN / 4, 256, 0, stream>>>(h, ln2g + l * DMODEL, ln2b + l * DMODEL, abuf);
    k_mm<2, 128, 64><<<dim3(DFF / 64, TKN / 128, 1), 256, 0, stream>>>(
        abuf, winT + l * wDF, bin + l * DFF, ffbuf, DFF, DMODEL);
    k_mm<1, 128, 64><<<dim3(DMODEL / 64, TKN / 128, 4), 256, 0, stream>>>(
        ffbuf, woutT + l * wDF, bout + l * DMODEL, h, DMODEL, DFF);
  }

  k_ln<<<TKN / 4, 256, 0, stream>>>(h, lnfg, lnfb, abuf);
  k_mm<3, 64, 64><<<dim3(NVOCAB / 64, TKN / 64, 1), 256, 0, stream>>>(
      abuf, outwT, nullptr, d_out, NVOCAB, DMODEL);
}